// Round 11
// baseline (90.053 us; speedup 1.0000x reference)
//
#include <hip/hip_runtime.h>
#include <hip/hip_bf16.h>
#include <cstdint>

// Problem constants
#define BROWS 8192
#define DIN   512
#define DH    1024
#define KTOT  1536          // DIN + DH
#define NT    (KTOT / 32)   // 48 K-tiles of 32
// Only gate columns [0,2048) are live: g block [0,1024), i block [1024,2048).
// (reference bug: f_out and o_out both use i_in -> f_in/o_in are dead)

typedef __bf16 bf16x8 __attribute__((ext_vector_type(8)));
typedef __bf16 bf16x4 __attribute__((ext_vector_type(4)));
typedef float  f32x4  __attribute__((ext_vector_type(4)));

__device__ __forceinline__ void load16_to_lds(const void* gptr, void* lptr) {
    __builtin_amdgcn_global_load_lds(
        (const __attribute__((address_space(1))) uint32_t*)gptr,
        (__attribute__((address_space(3))) uint32_t*)lptr,
        16, 0, 0);
}

// ---------- Kernel 1: convert x|h -> bf16 A[8192][48 kt][64B], PRE-SWIZZLED ----------
// 64B K-chunks (BK=32); within a chunk the 16B slot is XORed with ((row&3)<<4)
// so linear global_load_lds staging + swizzled ds_read spread evenly over banks.
__global__ __launch_bounds__(256) void cvtA_kernel(
    const float* __restrict__ x, const float* __restrict__ h,
    __bf16* __restrict__ A) {
    int t = blockIdx.x * 256 + threadIdx.x;   // 8192*192 units of 16B
    int row = t / 192;
    int j = t - row * 192;                    // 16B unit within row
    int kg = j * 8;                           // element offset
    const float* src = (kg < DIN) ? (x + (size_t)row * DIN + kg)
                                  : (h + (size_t)row * DH + (kg - DIN));
    float4 u = *(const float4*)src;
    float4 v = *(const float4*)(src + 4);
    bf16x8 o = { (__bf16)u.x, (__bf16)u.y, (__bf16)u.z, (__bf16)u.w,
                 (__bf16)v.x, (__bf16)v.y, (__bf16)v.z, (__bf16)v.w };
    int kt = j >> 2;                          // K-tile 0..47
    int cb = (j & 3) * 16;                    // 16B slot within 64B chunk
    int pos = kt * 64 + (cb ^ ((row & 3) << 4));
    *(bf16x8*)((char*)A + (size_t)row * 3072 + pos) = o;
}

// ---------- Kernel 2: transpose+convert W cols [0,2048) -> Bt[2048][48 kt][64B], PRE-SWIZZLED ----------
__global__ __launch_bounds__(256) void cvtB_kernel(
    const float* __restrict__ Wx, const float* __restrict__ Wh,
    __bf16* __restrict__ Bt) {
    __shared__ float tile[32][33];
    int k0 = blockIdx.x * 32;
    int n0 = blockIdx.y * 32;
    int tx = threadIdx.x;   // 0..31
    int ty = threadIdx.y;   // 0..7
#pragma unroll
    for (int i = 0; i < 4; ++i) {
        int k = k0 + ty + 8 * i;
        float v = (k < DIN) ? Wx[(size_t)k * 4096 + n0 + tx]
                            : Wh[(size_t)(k - DIN) * 4096 + n0 + tx];
        tile[ty + 8 * i][tx] = v;
    }
    __syncthreads();
    int n  = n0 + tx;
    int kk = ty * 4;                 // k-local 0..28 (k0 is 32-aligned)
    bf16x4 o = { (__bf16)tile[kk][tx], (__bf16)tile[kk + 1][tx],
                 (__bf16)tile[kk + 2][tx], (__bf16)tile[kk + 3][tx] };
    int kt = (k0 + kk) >> 5;
    int cbyte = kk * 2;              // 8B granule within 64B chunk
    int pos = kt * 64 + (cbyte ^ ((n & 3) << 4));   // XOR preserves bit 3
    *(bf16x4*)((char*)Bt + (size_t)n * 3072 + pos) = o;
}

// ---------- Kernel 3: BK=32 GEMM, 2 blocks/CU, 1 barrier/K-tile + fused epilogue ----------
// Tile 256(M) x 64(n') x {g,i}; B-tile = g 64 rows + i 64 rows = 128 x 32.
// LDS = (16+8) KiB x 2 = 48 KiB -> 2 blocks/CU; 8 waves = 4M x 2N, wave =
// 64M x 32n' x {g,i}: acc 64 VGPR -> ~120 total -> 4 waves/SIMD.
// Per tile: VMW(0)+BARRIER (drains loads issued a FULL tile ago), 8 ds_read,
// stage(t+1) 3 loads, LGKM0, 16 MFMA. Two desynced blocks cross-fill stalls.
// STAGING LAW (m104): every global_load_lds's per-lane LDS ptr MUST equal
// chunkBase + lane*16. Each macro below assigns lane -> (row = base+(lane>>2),
// slot = lane&3), i.e. 16 consecutive 64B rows = one 1024B wave chunk.

#define BARRIER  do { __builtin_amdgcn_sched_barrier(0); __builtin_amdgcn_s_barrier(); __builtin_amdgcn_sched_barrier(0); } while (0)
#define VMW0     do { asm volatile("s_waitcnt vmcnt(0)" ::: "memory"); __builtin_amdgcn_sched_barrier(0); } while (0)
#define LGKM0    do { asm volatile("s_waitcnt lgkmcnt(0)" ::: "memory"); __builtin_amdgcn_sched_barrier(0); } while (0)

// A: 16 KiB/tile; wave w stages rows [32w, 32w+32) as two 16-row chunks.
#define STAGE_A(buf, kt) do {                                                  \
    _Pragma("unroll")                                                          \
    for (int p_ = 0; p_ < 2; ++p_) {                                           \
        int row_ = wid * 32 + p_ * 16 + (lane >> 2);                           \
        const char* g_ = Ab + (size_t)(brow + row_) * 3072                     \
                            + (kt) * 64 + (lane & 3) * 16;                     \
        load16_to_lds(g_, sAb + (buf) * 24576 + row_ * 64 + (lane & 3) * 16);  \
    }                                                                          \
    __builtin_amdgcn_sched_barrier(0);                                         \
} while (0)

// B: 8 KiB/tile; wave w stages B-rows [16w, 16w+16) (rows 0-63 g, 64-127 i).
#define STAGE_B(buf, kt) do {                                                  \
    load16_to_lds(Bb + (size_t)gcolB * 3072 + (kt) * 64 + (lane & 3) * 16,     \
                  sAb + (buf) * 24576 + 16384 + rB * 64 + (lane & 3) * 16);    \
    __builtin_amdgcn_sched_barrier(0);                                         \
} while (0)

#define READ_A(c)                                                              \
    _Pragma("unroll")                                                          \
    for (int m_ = 0; m_ < 4; ++m_) {                                           \
        aF[m_] = *(const bf16x8*)(sAb + (c) * 24576 + m_ * 1024 + rdA);        \
    }

#define READ_B(c)                                                              \
    _Pragma("unroll")                                                          \
    for (int n_ = 0; n_ < 2; ++n_) {                                           \
        bgF[n_] = *(const bf16x8*)(sAb + (c) * 24576 + 16384 + n_ * 1024 + rdB); \
        biF[n_] = *(const bf16x8*)(sAb + (c) * 24576 + 16384 + 4096            \
                                   + n_ * 1024 + rdB);                         \
    }

#define MMA_ALL() do {                                                         \
    _Pragma("unroll")                                                          \
    for (int m_ = 0; m_ < 4; ++m_) {                                           \
        _Pragma("unroll")                                                      \
        for (int n_ = 0; n_ < 2; ++n_) {                                       \
            accg[m_][n_] = __builtin_amdgcn_mfma_f32_16x16x32_bf16(            \
                aF[m_], bgF[n_], accg[m_][n_], 0, 0, 0);                       \
            acci[m_][n_] = __builtin_amdgcn_mfma_f32_16x16x32_bf16(            \
                aF[m_], biF[n_], acci[m_][n_], 0, 0, 0);                       \
        }                                                                      \
    }                                                                          \
    __builtin_amdgcn_sched_barrier(0);                                         \
} while (0)

__global__ __launch_bounds__(512, 4) void lstm_gemm_kernel(
    const __bf16* __restrict__ A,    // [8192][48][64B] pre-swizzled
    const __bf16* __restrict__ Bt,   // [2048][48][64B] pre-swizzled
    const float* __restrict__ bias,  // [4096]
    const float* __restrict__ c_in,  // [8192][1024]
    float* __restrict__ out_h,       // [8192][1024]
    float* __restrict__ out_c) {     // [8192][1024]
    // Layout per buffer (24576 B): A tile [0,16384) rows 0-255 x 64B;
    //                              B tile [16384,24576) rows 0-127 x 64B.
    __shared__ char smem[49152];

    const int tid  = threadIdx.x;
    const int lane = tid & 63;
    const int wid  = tid >> 6;
    const int wr   = wid & 3;          // 4 wave-rows (M)
    const int wc   = wid >> 2;         // 2 wave-cols (n')

    // XCD-contiguous band map: XCD x (= bid%8) owns M-bands [4x, 4x+4);
    // panel (16 of 64 n'-cols) slow index. A slice/XCD = 3 MB (L2-resident).
    const int bid   = blockIdx.x;                        // 0..511
    const int band  = (bid & 7) * 4 + ((bid >> 3) & 3);  // 0..31
    const int panel = bid >> 5;                          // 0..15
    const int brow  = band * 256;
    const int bnp   = panel * 64;

    const int l15 = lane & 15;
    const int l4  = lane >> 4;

    // B staging: wave wid stages B-rows [16*wid, 16*wid+16)
    const int rB    = wid * 16 + (lane >> 2);
    const int gcolB = (rB < 64) ? (bnp + rB) : (1024 + bnp + (rB - 64));

    // ds_read per-lane byte offsets (row -> +((row&3)<<4) XOR on the 16B slot)
    const int swz  = (l15 & 3) << 4;
    const int rdA  = (wr * 64 + l15) * 64 + ((l4 * 16) ^ swz);
    const int rdB  = (wc * 32 + l15) * 64 + ((l4 * 16) ^ swz);

    const char* Ab = (const char*)A;
    const char* Bb = (const char*)Bt;
    char* sAb = smem;

    f32x4 accg[4][2], acci[4][2];
#pragma unroll
    for (int mi = 0; mi < 4; ++mi)
#pragma unroll
        for (int ni = 0; ni < 2; ++ni) {
            accg[mi][ni] = (f32x4){0.f, 0.f, 0.f, 0.f};
            acci[mi][ni] = (f32x4){0.f, 0.f, 0.f, 0.f};
        }

    bf16x8 aF[4], bgF[2], biF[2];

    STAGE_A(0, 0);                       // 2 loads
    STAGE_B(0, 0);                       // 1 load

    for (int t = 0; t < NT - 1; ++t) {
        const int c  = t & 1;
        const int nb = c ^ 1;
        VMW0;                            // drain stage(t) (issued 1 tile ago)
        BARRIER;                         // whole tile staged, all waves
        READ_A(c);                       // 4 ds_read_b128
        READ_B(c);                       // 4 ds_read_b128
        STAGE_A(nb, t + 1);              // 3 loads -> other buffer
        STAGE_B(nb, t + 1);
        LGKM0;
        MMA_ALL();                       // 16 MFMA
    }
    {   // last tile
        const int c = (NT - 1) & 1;
        VMW0;
        BARRIER;
        READ_A(c);
        READ_B(c);
        LGKM0;
        MMA_ALL();
    }

    // Epilogue: s = sigmoid(i_in); t = tanh(g_in); c_new = s*(t+c); h_new = tanh(c_new)*s
    const int R0 = brow + wr * 64;
    const int C0 = bnp + wc * 32;
#pragma unroll
    for (int ni = 0; ni < 2; ++ni) {
        const int col = C0 + ni * 16 + l15;
        const float bg = bias[col];
        const float bi = bias[1024 + col];
#pragma unroll
        for (int mi = 0; mi < 4; ++mi) {
#pragma unroll
            for (int r = 0; r < 4; ++r) {
                const int row = R0 + mi * 16 + l4 * 4 + r;
                const float g_in = accg[mi][ni][r] + bg;
                const float i_in = acci[mi][ni][r] + bi;
                const float s  = 1.0f / (1.0f + __expf(-i_in));
                const float tg = 2.0f / (1.0f + __expf(-2.0f * g_in)) - 1.0f;
                const float cv = c_in[(size_t)row * DH + col];
                const float cn = s * (tg + cv);
                const float hn = (2.0f / (1.0f + __expf(-2.0f * cn)) - 1.0f) * s;
                out_h[(size_t)row * DH + col] = hn;
                out_c[(size_t)row * DH + col] = cn;
            }
        }
    }
}

extern "C" void kernel_launch(void* const* d_in, const int* in_sizes, int n_in,
                              void* d_out, int out_size, void* d_ws, size_t ws_size,
                              hipStream_t stream) {
    const float* x  = (const float*)d_in[0];
    const float* h  = (const float*)d_in[1];
    const float* c  = (const float*)d_in[2];
    const float* Wx = (const float*)d_in[3];
    const float* Wh = (const float*)d_in[4];
    const float* b  = (const float*)d_in[5];

    __bf16* A  = (__bf16*)d_ws;                                     // 25,165,824 B
    __bf16* Bt = (__bf16*)((char*)d_ws + (size_t)BROWS * KTOT * 2); // 6,291,456 B

    float* out_h = (float*)d_out;
    float* out_c = out_h + (size_t)BROWS * DH;

    cvtA_kernel<<<(BROWS * (KTOT / 8)) / 256, 256, 0, stream>>>(x, h, A);
    cvtB_kernel<<<dim3(KTOT / 32, 2048 / 32), dim3(32, 8), 0, stream>>>(Wx, Wh, Bt);
    lstm_gemm_kernel<<<512, 512, 0, stream>>>(A, Bt, b, c, out_h, out_c);
}

// Round 12
// 84.131 us; speedup vs baseline: 1.0704x; 1.0704x over previous
//
#include <hip/hip_runtime.h>
#include <hip/hip_bf16.h>
#include <cstdint>

// Problem constants
#define BROWS 8192
#define DIN   512
#define DH    1024
#define KTOT  1536          // DIN + DH
#define NT    (KTOT / 64)   // 24 K-tiles of 64
// Only gate columns [0,2048) are live: g block [0,1024), i block [1024,2048).
// (reference bug: f_out and o_out both use i_in -> f_in/o_in are dead)

typedef __bf16 bf16x8 __attribute__((ext_vector_type(8)));
typedef __bf16 bf16x4 __attribute__((ext_vector_type(4)));
typedef float  f32x4  __attribute__((ext_vector_type(4)));

__device__ __forceinline__ void load16_to_lds(const void* gptr, void* lptr) {
    __builtin_amdgcn_global_load_lds(
        (const __attribute__((address_space(1))) uint32_t*)gptr,
        (__attribute__((address_space(3))) uint32_t*)lptr,
        16, 0, 0);
}

// ---------- Kernel 1: convert x|h -> bf16 A[8192][1536], PRE-SWIZZLED ----------
// (R4-proven: XOR-8 on the 16B slot within each 128B K-chunk -> 0 bank conflicts)
__global__ __launch_bounds__(256) void cvtA_kernel(
    const float* __restrict__ x, const float* __restrict__ h,
    __bf16* __restrict__ A) {
    int t = blockIdx.x * 256 + threadIdx.x;   // 8192*192 units of 16B
    int row = t / 192;
    int j = t - row * 192;
    int kg = j * 8;
    const float* src = (kg < DIN) ? (x + (size_t)row * DIN + kg)
                                  : (h + (size_t)row * DH + (kg - DIN));
    float4 u = *(const float4*)src;
    float4 v = *(const float4*)(src + 4);
    bf16x8 o = { (__bf16)u.x, (__bf16)u.y, (__bf16)u.z, (__bf16)u.w,
                 (__bf16)v.x, (__bf16)v.y, (__bf16)v.z, (__bf16)v.w };
    int swz = (j * 16) ^ ((row & 7) << 4);
    *(bf16x8*)((char*)A + (size_t)row * 3072 + swz) = o;
}

// ---------- Kernel 2: transpose+convert W cols [0,2048) -> bf16 Bt[2048][1536], PRE-SWIZZLED ----------
__global__ __launch_bounds__(256) void cvtB_kernel(
    const float* __restrict__ Wx, const float* __restrict__ Wh,
    __bf16* __restrict__ Bt) {
    __shared__ float tile[32][33];
    int k0 = blockIdx.x * 32;
    int n0 = blockIdx.y * 32;
    int tx = threadIdx.x;   // 0..31
    int ty = threadIdx.y;   // 0..7
#pragma unroll
    for (int i = 0; i < 4; ++i) {
        int k = k0 + ty + 8 * i;
        float v = (k < DIN) ? Wx[(size_t)k * 4096 + n0 + tx]
                            : Wh[(size_t)(k - DIN) * 4096 + n0 + tx];
        tile[ty + 8 * i][tx] = v;
    }
    __syncthreads();
    int n = n0 + tx;
    int kk = ty * 4;
    bf16x4 o = { (__bf16)tile[kk][tx], (__bf16)tile[kk + 1][tx],
                 (__bf16)tile[kk + 2][tx], (__bf16)tile[kk + 3][tx] };
    int swz = ((k0 + kk) * 2) ^ ((n & 7) << 4);
    *(bf16x4*)((char*)Bt + (size_t)n * 3072 + swz) = o;
}

// ---------- Kernel 3: 128x64{g,i} GEMM, 2 blocks/CU, fused LSTM epilogue ----------
// Block: 256 thr = 4 waves (2M x 2N'); wave tile 64M x 32n' x {g,i}:
//   reads/MFMA = (8 A + 8 B)/(32 MFMA) = 0.5 -> LDS 1.24x MFMA (vs R5's 1.9x).
// LDS: A 2x128x64x2B = 32K + B 2x128x64x2B = 32K = 64 KiB -> 2 blocks/CU;
// grid 1024 = 2 resident x 2 generations -> desynced partner hides barriers,
// next generation's loop hides this one's 100MB epilogue.
// Per-tile VMEM queue (per thread): [A x4][Bg x2][Bi x2].
//   P1 needs A,Bg -> VMW(2); P2 needs Bi (queue [Bi2,A'4]=6) -> VMW(4);
//   tail: VMW(0). Buffer WAR hazard covered by per-wave LGKM0 before the
//   next tile's first BARRIER (same proof as R4/R5).

#define BARRIER  do { __builtin_amdgcn_sched_barrier(0); __builtin_amdgcn_s_barrier(); __builtin_amdgcn_sched_barrier(0); } while (0)
#define VMW(n)   do { asm volatile("s_waitcnt vmcnt(" #n ")" ::: "memory"); __builtin_amdgcn_sched_barrier(0); } while (0)
#define LGKM0    do { asm volatile("s_waitcnt lgkmcnt(0)" ::: "memory"); __builtin_amdgcn_sched_barrier(0); } while (0)

// A: 16 KiB/tile, 4 issues of 32 rows (lane -> row lane>>3, slot lane&7: LAW ok)
#define STAGE_A(buf, kt) do {                                                  \
    _Pragma("unroll")                                                          \
    for (int p_ = 0; p_ < 4; ++p_) {                                           \
        int row_ = p_ * 32 + r0;                                               \
        load16_to_lds(Ab + (size_t)(brow + row_) * 3072 + (kt) * 128 + cb,     \
                      sAb + (buf) * 32768 + row_ * 128 + cb);                  \
    }                                                                          \
    __builtin_amdgcn_sched_barrier(0);                                         \
} while (0)

// Bg: 8 KiB/tile (gate-cols bnp..bnp+64 -> B-LDS rows 0..63)
#define STAGE_BG(buf, kt) do {                                                 \
    _Pragma("unroll")                                                          \
    for (int p_ = 0; p_ < 2; ++p_) {                                           \
        int row_ = p_ * 32 + r0;                                               \
        load16_to_lds(Bb + (size_t)(bnp + row_) * 3072 + (kt) * 128 + cb,      \
                      sAb + (buf) * 32768 + 16384 + row_ * 128 + cb);          \
    }                                                                          \
    __builtin_amdgcn_sched_barrier(0);                                         \
} while (0)

// Bi: 8 KiB/tile (gate-cols 1024+bnp.. -> B-LDS rows 64..127)
#define STAGE_BI(buf, kt) do {                                                 \
    _Pragma("unroll")                                                          \
    for (int p_ = 0; p_ < 2; ++p_) {                                           \
        int row_ = p_ * 32 + r0;                                               \
        load16_to_lds(Bb + (size_t)(1024 + bnp + row_) * 3072                  \
                          + (kt) * 128 + cb,                                   \
                      sAb + (buf) * 32768 + 16384 + (64 + row_) * 128 + cb);   \
    }                                                                          \
    __builtin_amdgcn_sched_barrier(0);                                         \
} while (0)

#define READ_A(c)                                                              \
    _Pragma("unroll")                                                          \
    for (int m_ = 0; m_ < 4; ++m_) {                                           \
        _Pragma("unroll")                                                      \
        for (int ks_ = 0; ks_ < 2; ++ks_) {                                    \
            aF[m_][ks_] = *(const bf16x8*)(sAb + (c) * 32768                   \
                + (wrow + m_ * 16 + l15) * 128                                 \
                + ((ks_ * 64 + l4x16) ^ swzkey));                              \
        }                                                                      \
    }

#define READ_BG(c)                                                             \
    _Pragma("unroll")                                                          \
    for (int n_ = 0; n_ < 2; ++n_) {                                           \
        _Pragma("unroll")                                                      \
        for (int ks_ = 0; ks_ < 2; ++ks_) {                                    \
            bgF[n_][ks_] = *(const bf16x8*)(sAb + (c) * 32768 + 16384          \
                + (wcol + n_ * 16 + l15) * 128                                 \
                + ((ks_ * 64 + l4x16) ^ swzkey));                              \
        }                                                                      \
    }

#define READ_BI(c)                                                             \
    _Pragma("unroll")                                                          \
    for (int n_ = 0; n_ < 2; ++n_) {                                           \
        _Pragma("unroll")                                                      \
        for (int ks_ = 0; ks_ < 2; ++ks_) {                                    \
            biF[n_][ks_] = *(const bf16x8*)(sAb + (c) * 32768 + 16384          \
                + (64 + wcol + n_ * 16 + l15) * 128                            \
                + ((ks_ * 64 + l4x16) ^ swzkey));                              \
        }                                                                      \
    }

#define MMA(ACC, BF) do {                                                      \
    __builtin_amdgcn_s_setprio(1);                                             \
    _Pragma("unroll")                                                          \
    for (int ks_ = 0; ks_ < 2; ++ks_) {                                        \
        _Pragma("unroll")                                                      \
        for (int m_ = 0; m_ < 4; ++m_) {                                       \
            _Pragma("unroll")                                                  \
            for (int n_ = 0; n_ < 2; ++n_) {                                   \
                ACC[m_][n_] = __builtin_amdgcn_mfma_f32_16x16x32_bf16(         \
                    aF[m_][ks_], BF[n_][ks_], ACC[m_][n_], 0, 0, 0);           \
            }                                                                  \
        }                                                                      \
    }                                                                          \
    __builtin_amdgcn_s_setprio(0);                                             \
    __builtin_amdgcn_sched_barrier(0);                                         \
} while (0)

__global__ __launch_bounds__(256, 2) void lstm_gemm_kernel(
    const __bf16* __restrict__ A,    // [8192][1536] pre-swizzled
    const __bf16* __restrict__ Bt,   // [2048][1536] pre-swizzled
    const float* __restrict__ bias,  // [4096]
    const float* __restrict__ c_in,  // [8192][1024]
    float* __restrict__ out_h,       // [8192][1024]
    float* __restrict__ out_c) {     // [8192][1024]
    // Per buffer (32768 B): A rows 0-127 x 128B at [0,16384);
    //                       B rows 0-127 (g 0-63 | i 64-127) at [16384,32768).
    __shared__ char smem[65536];

    const int tid  = threadIdx.x;
    const int lane = tid & 63;
    const int wid  = tid >> 6;
    const int wr   = wid & 1;          // 2 wave-rows (M)
    const int wc   = wid >> 1;         // 2 wave-cols (n')

    // XCD map: XCD x (= bid%8) owns bands [8x, 8x+8) (A slice 3 MB, L2);
    // band fast within XCD, panel slow.
    const int bid   = blockIdx.x;                  // 0..1023
    const int q     = bid >> 3;                    // 0..127
    const int band  = (bid & 7) * 8 + (q & 7);     // 0..63
    const int panel = q >> 3;                      // 0..15
    const int brow  = band * 128;
    const int bnp   = panel * 64;

    const int l15    = lane & 15;
    const int l4x16  = (lane >> 4) * 16;
    const int swzkey = (l15 & 7) << 4;
    const int wrow   = wr * 64;
    const int wcol   = wc * 32;

    // staging lane mapping: LDS dst = wave-uniform base + lane*16
    const int r0 = tid >> 3;           // 0..31
    const int cb = (tid & 7) * 16;     // 0..112

    const char* Ab = (const char*)A;
    const char* Bb = (const char*)Bt;
    char* sAb = smem;

    f32x4 accg[4][2], acci[4][2];
#pragma unroll
    for (int mi = 0; mi < 4; ++mi)
#pragma unroll
        for (int ni = 0; ni < 2; ++ni) {
            accg[mi][ni] = (f32x4){0.f, 0.f, 0.f, 0.f};
            acci[mi][ni] = (f32x4){0.f, 0.f, 0.f, 0.f};
        }

    bf16x8 aF[4][2], bgF[2][2], biF[2][2];

    // prologue: stage tile 0. Queue order per tile: A(4), Bg(2), Bi(2).
    STAGE_A(0, 0);
    STAGE_BG(0, 0);
    STAGE_BI(0, 0);

    for (int t = 0; t < NT - 1; ++t) {
        const int c  = t & 1;
        const int nb = c ^ 1;
        // P1: needs A, Bg of tile t (oldest 6 of 8 in flight)
        VMW(2); BARRIER;
        READ_A(c);
        READ_BG(c);
        STAGE_A(nb, t + 1);
        LGKM0;
        MMA(accg, bgF);
        // P2: needs Bi of tile t (queue: [Bi(t)2, A(t+1)4] = 6)
        VMW(4); BARRIER;
        READ_BI(c);
        STAGE_BG(nb, t + 1);
        STAGE_BI(nb, t + 1);
        LGKM0;
        MMA(acci, biF);
    }
    {   // last tile: drain all, no prefetch
        const int c = (NT - 1) & 1;
        VMW(0); BARRIER;
        READ_A(c);
        READ_BG(c);
        READ_BI(c);
        LGKM0;
        MMA(accg, bgF);
        MMA(acci, biF);
    }

    // Epilogue: s = sigmoid(i_in); t = tanh(g_in); c_new = s*(t+c); h_new = tanh(c_new)*s
    const int R0 = brow + wrow;
    const int C0 = bnp + wcol;
    const int l4 = lane >> 4;
#pragma unroll
    for (int ni = 0; ni < 2; ++ni) {
        const int col = C0 + ni * 16 + l15;
        const float bg = bias[col];
        const float bi = bias[1024 + col];
#pragma unroll
        for (int mi = 0; mi < 4; ++mi) {
#pragma unroll
            for (int r = 0; r < 4; ++r) {
                const int row = R0 + mi * 16 + l4 * 4 + r;
                const float g_in = accg[mi][ni][r] + bg;
                const float i_in = acci[mi][ni][r] + bi;
                const float s  = 1.0f / (1.0f + __expf(-i_in));
                const float tg = 2.0f / (1.0f + __expf(-2.0f * g_in)) - 1.0f;
                const float cv = c_in[(size_t)row * DH + col];
                const float cn = s * (tg + cv);
                const float hn = (2.0f / (1.0f + __expf(-2.0f * cn)) - 1.0f) * s;
                out_h[(size_t)row * DH + col] = hn;
                out_c[(size_t)row * DH + col] = cn;
            }
        }
    }
}

extern "C" void kernel_launch(void* const* d_in, const int* in_sizes, int n_in,
                              void* d_out, int out_size, void* d_ws, size_t ws_size,
                              hipStream_t stream) {
    const float* x  = (const float*)d_in[0];
    const float* h  = (const float*)d_in[1];
    const float* c  = (const float*)d_in[2];
    const float* Wx = (const float*)d_in[3];
    const float* Wh = (const float*)d_in[4];
    const float* b  = (const float*)d_in[5];

    __bf16* A  = (__bf16*)d_ws;                                     // 25,165,824 B
    __bf16* Bt = (__bf16*)((char*)d_ws + (size_t)BROWS * KTOT * 2); // 6,291,456 B

    float* out_h = (float*)d_out;
    float* out_c = out_h + (size_t)BROWS * DH;

    cvtA_kernel<<<(BROWS * (KTOT / 8)) / 256, 256, 0, stream>>>(x, h, A);
    cvtB_kernel<<<dim3(KTOT / 32, 2048 / 32), dim3(32, 8), 0, stream>>>(Wx, Wh, Bt);
    lstm_gemm_kernel<<<1024, 256, 0, stream>>>(A, Bt, b, c, out_h, out_c);
}